// Round 7
// baseline (506.303 us; speedup 1.0000x reference)
//
#include <hip/hip_runtime.h>
#include <math.h>

// Problem constants (from reference): T=256, NB=64, NCLASS=7357, L=50
#define TT 256
#define NB 64
#define NC 7357
#define LL 50
#define NROWS (TT * NB)   // 16384
#define NBLK 2048         // persistent blocks
#define ROWS_PER_WAVE 2   // 2048 blk * 4 waves * 2 = 16384 rows
#define PASSES 6          // DIAGNOSTIC v2: re-read input 6x with a CSE-proof
                          // opaque offset per pass. accs=6S, accz=6Z ->
                          // 1 - accz/accs == 1 - Z/S (exact in ratio).
                          // Guarantees row_kernel > fill dur -> counters visible.

typedef float f32x4 __attribute__((ext_vector_type(4)));

// ---------------------------------------------------------------------------
// Kernel 1: build per-batch unique zeroed-class lists.
// ---------------------------------------------------------------------------
__global__ void prep_kernel(const int* __restrict__ target,
                            int* __restrict__ nz, int* __restrict__ cls) {
    int b = threadIdx.x;
    if (b >= NB) return;
    int list[LL + 1];
    int n = 0;
    list[n++] = 0;  // class 0 always zeroed
    for (int j = 0; j < LL; ++j) {
        int t = target[b * LL + j];
        if (t == 0) break;  // cumprod validity: stop at first 0
        bool found = false;
        for (int k = 0; k < n; ++k) {
            if (list[k] == t) { found = true; break; }
        }
        if (!found) list[n++] = t;
    }
    nz[b] = n;
    for (int k = 0; k < n; ++k) cls[b * 64 + k] = list[k];
}

__device__ __forceinline__ float fexp(float v) { return __expf(v); }

// ---------------------------------------------------------------------------
// Kernel 2: persistent wave-per-row, PASSES x over the data, NT loads.
// Per-pass base pointer is made opaque via empty inline asm so the compiler
// CANNOT CSE/fold the repeated passes (R5's diagnostic was invalidated by
// exactly that). Structure otherwise identical to the R6 kernel.
// ---------------------------------------------------------------------------
__global__ __launch_bounds__(256, 4) void row_kernel(const float* __restrict__ x,
                                                     const int* __restrict__ nz,
                                                     const int* __restrict__ cls,
                                                     float* __restrict__ partial) {
    const int lane = threadIdx.x & 63;
    const int gwave = (blockIdx.x << 2) | (threadIdx.x >> 6);  // 0..8191

    float accs[ROWS_PER_WAVE], accz[ROWS_PER_WAVE];
#pragma unroll
    for (int r = 0; r < ROWS_PER_WAVE; ++r) { accs[r] = 0.0f; accz[r] = 0.0f; }

    for (int pass = 0; pass < PASSES; ++pass) {
        // Opaque zero: compiler must treat each pass's loads as new addresses.
        int off = 0;
        asm volatile("" : "+v"(off));
        const float* xb = x + off;

#pragma unroll
        for (int r = 0; r < ROWS_PER_WAVE; ++r) {
            const int row = gwave * ROWS_PER_WAVE + r;   // 0..16383
            const int b = row & (NB - 1);
            const float* rp = xb + (size_t)row * NC;

            // Row byte offset = row*29428; %16 == row*4 -> peel to 16B align.
            const int peel = (4 - (row & 3)) & 3;
            const int rem = NC - peel;
            const int nvec = rem >> 2;        // 1838 or 1839
            const int tail = rem & 3;
            const f32x4* vp = (const f32x4*)(rp + peel);

            // zeroed-class gather (<=51 lanes)
            const int n = nz[b];
            float xg = (lane < n) ? rp[cls[b * 64 + lane]] : -INFINITY;

            // peel / tail leftovers (default -inf -> exp = 0)
            float ex1 = (lane < peel) ? rp[lane] : -INFINITY;
            float ex2 = (lane < tail) ? rp[peel + (nvec << 2) + lane] : -INFINITY;

            float s = fexp(ex1) + fexp(ex2);

            // 28 full wave-iterations (28*64 = 1792 <= 1838): 7 chunks of 4.
            int i = lane;
#pragma unroll
            for (int c = 0; c < 7; ++c) {
                f32x4 q0 = __builtin_nontemporal_load(vp + i);
                f32x4 q1 = __builtin_nontemporal_load(vp + i + 64);
                f32x4 q2 = __builtin_nontemporal_load(vp + i + 128);
                f32x4 q3 = __builtin_nontemporal_load(vp + i + 192);
                s += fexp(q0.x) + fexp(q0.y) + fexp(q0.z) + fexp(q0.w);
                s += fexp(q1.x) + fexp(q1.y) + fexp(q1.z) + fexp(q1.w);
                s += fexp(q2.x) + fexp(q2.y) + fexp(q2.z) + fexp(q2.w);
                s += fexp(q3.x) + fexp(q3.y) + fexp(q3.z) + fexp(q3.w);
                i += 256;
            }
            // partial 29th iteration (46 or 47 active lanes)
            if (i < nvec) {
                f32x4 q = __builtin_nontemporal_load(vp + i);
                s += fexp(q.x) + fexp(q.y) + fexp(q.z) + fexp(q.w);
            }

            accs[r] += s;
            accz[r] += fexp(xg);
        }
    }

    // wave-only reductions (width 64), once per row
#pragma unroll
    for (int r = 0; r < ROWS_PER_WAVE; ++r) {
        float s = accs[r], z = accz[r];
        for (int o = 32; o > 0; o >>= 1) {
            s += __shfl_down(s, o);
            z += __shfl_down(z, o);
        }
        if (lane == 0) {
            const int row = gwave * ROWS_PER_WAVE + r;
            partial[row] = 1.0f - z / s;
        }
    }
}

// ---------------------------------------------------------------------------
// Kernel 3: deterministic final reduce of 16384 partials -> scalar loss.
// ---------------------------------------------------------------------------
__global__ __launch_bounds__(256) void final_kernel(const float* __restrict__ partial,
                                                    float* __restrict__ out) {
    const f32x4* p4 = (const f32x4*)partial;  // 4096 vectors
    float s = 0.0f;
    int i = threadIdx.x;
#pragma unroll
    for (int c = 0; c < 16; ++c) {  // 16 * 256 = 4096
        f32x4 q = p4[i];
        s += q.x + q.y + q.z + q.w;
        i += 256;
    }
    for (int o = 32; o > 0; o >>= 1) s += __shfl_down(s, o);
    __shared__ float sr[4];
    if ((threadIdx.x & 63) == 0) sr[threadIdx.x >> 6] = s;
    __syncthreads();
    if (threadIdx.x == 0)
        out[0] = (sr[0] + sr[1] + sr[2] + sr[3]) * (1.0f / ((float)NB * (float)NC));
}

extern "C" void kernel_launch(void* const* d_in, const int* in_sizes, int n_in,
                              void* d_out, int out_size, void* d_ws, size_t ws_size,
                              hipStream_t stream) {
    const float* dense_pred = (const float*)d_in[0];
    const int* target = (const int*)d_in[1];
    float* out = (float*)d_out;

    // Workspace layout
    int* nz = (int*)d_ws;                     //   64 ints   (bytes 0..255)
    int* cls = nz + 64;                       //   4096 ints (bytes 256..16639)
    float* partial = (float*)(cls + 64 * 64); //   16384 floats @ byte 16640 (16B aligned)

    prep_kernel<<<1, 64, 0, stream>>>(target, nz, cls);
    row_kernel<<<NBLK, 256, 0, stream>>>(dense_pred, nz, cls, partial);
    final_kernel<<<1, 256, 0, stream>>>(partial, out);
}

// Round 8
// 208.378 us; speedup vs baseline: 2.4297x; 2.4297x over previous
//
#include <hip/hip_runtime.h>
#include <math.h>

// Problem constants: T=256, NB=64, NCLASS=7357, L=50
#define TT 256
#define NB 64
#define NC 7357
#define LL 50
#define NROWS (TT * NB)           // 16384
#define NFLOAT (NROWS * NC)       // 120,537,088 floats == 256 * 470,848 exactly
#define NWIN (NFLOAT / 256)       // 470,848 wave-windows (no tail!)
#define NBLK 2048

typedef float f32x4 __attribute__((ext_vector_type(4)));

// ---------------------------------------------------------------------------
// Kernel 1: per-batch unique zeroed-class lists.
// ---------------------------------------------------------------------------
__global__ void prep_kernel(const int* __restrict__ target,
                            int* __restrict__ nz, int* __restrict__ cls) {
    int b = threadIdx.x;
    if (b >= NB) return;
    int list[LL + 1];
    int n = 0;
    list[n++] = 0;
    for (int j = 0; j < LL; ++j) {
        int t = target[b * LL + j];
        if (t == 0) break;
        bool found = false;
        for (int k = 0; k < n; ++k)
            if (list[k] == t) { found = true; break; }
        if (!found) list[n++] = t;
    }
    nz[b] = n;
    for (int k = 0; k < n; ++k) cls[b * 64 + k] = list[k];
}

__device__ __forceinline__ float fexp(float v) { return __expf(v); }

// ---------------------------------------------------------------------------
// Kernel 2 (PHASE 1): copy-pattern grid-stride sweep. Each wave-iteration
// covers 256 CONTIGUOUS floats (64 lanes x float4); device-wide the active
// addresses form one compact window marching through memory — same DRAM
// pattern as the 6.7 TB/s fill kernel, vs ~3600 scattered row-streams that
// measured 3.16 TB/s (R7). A 256-float window spans at most ONE row boundary
// (256 < 7357): wave writes float2{sumA within first row, sumB within next}.
// ---------------------------------------------------------------------------
__global__ __launch_bounds__(256, 4) void stream_kernel(const float* __restrict__ x,
                                                        float2* __restrict__ win) {
    const int lane = threadIdx.x & 63;
    const int gwave = (blockIdx.x << 2) | (threadIdx.x >> 6);  // 0..8191
    const f32x4* vp = (const f32x4*)x;

    for (int u = gwave; u < NWIN; u += 8192) {
        f32x4 q = __builtin_nontemporal_load(vp + ((size_t)u * 64 + lane));
        float e0 = fexp(q.x), e1 = fexp(q.y), e2 = fexp(q.z), e3 = fexp(q.w);

        const int fbase = u << 8;             // first flat float idx of window
        const int r1 = fbase / NC;            // row of first element
        const int r2 = (fbase + 255) / NC;    // row of last element
        float sA, sB;
        if (r1 == r2) {                       // 96.5% of windows, wave-uniform
            sA = (e0 + e1) + (e2 + e3);
            for (int o = 32; o > 0; o >>= 1) sA += __shfl_down(sA, o);
            sB = 0.0f;
        } else {                              // boundary window: split at B
            const int B = r2 * NC;            // first float idx of row r2
            const int f0 = fbase + (lane << 2);
            sA = 0.0f; sB = 0.0f;
            if (f0 + 0 < B) sA += e0; else sB += e0;
            if (f0 + 1 < B) sA += e1; else sB += e1;
            if (f0 + 2 < B) sA += e2; else sB += e2;
            if (f0 + 3 < B) sA += e3; else sB += e3;
            for (int o = 32; o > 0; o >>= 1) {
                sA += __shfl_down(sA, o);
                sB += __shfl_down(sB, o);
            }
        }
        if (lane == 0) win[u] = make_float2(sA, sB);  // regular store: stays cached for phase 2
    }
}

// ---------------------------------------------------------------------------
// Kernel 3 (PHASE 2): one wave per row. Lanes 0..29 pick up this row's window
// contributions (3.8 MB, cache-hot); lanes 0..n-1 gather the <=51 zeroed-class
// elements; joint shfl reduce; partial[row] = 1 - Z/S. Deterministic.
// ---------------------------------------------------------------------------
__global__ __launch_bounds__(256) void row2_kernel(const float* __restrict__ x,
                                                   const float2* __restrict__ win,
                                                   const int* __restrict__ nz,
                                                   const int* __restrict__ cls,
                                                   float* __restrict__ partial) {
    const int lane = threadIdx.x & 63;
    const int wave = threadIdx.x >> 6;
    const int row = (blockIdx.x << 2) | wave;   // grid 4096 -> rows 0..16383
    const int b = row & (NB - 1);

    const int f0 = row * NC;
    const int u0 = f0 >> 8;                     // first window touching row
    const int u1 = (f0 + NC - 1) >> 8;          // last window touching row

    float S = 0.0f;
    const int u = u0 + lane;
    if (u <= u1) {                              // <=30 active lanes
        float2 w = win[u];
        const int fb = u << 8;
        const int r1 = fb / NC;
        const int r2 = (fb + 255) / NC;
        if (r1 == row) S += w.x;
        if (r2 == row && r1 != row) S += w.y;
    }

    // zeroed-class gather
    const int n = nz[b];
    float z = 0.0f;
    if (lane < n) z = fexp(x[(size_t)f0 + cls[b * 64 + lane]]);

    for (int o = 32; o > 0; o >>= 1) {
        S += __shfl_down(S, o);
        z += __shfl_down(z, o);
    }
    if (lane == 0) partial[row] = 1.0f - z / S;
}

// ---------------------------------------------------------------------------
// Kernel 4: deterministic final reduce of 16384 partials -> scalar loss.
// ---------------------------------------------------------------------------
__global__ __launch_bounds__(256) void final_kernel(const float* __restrict__ partial,
                                                    float* __restrict__ out) {
    const f32x4* p4 = (const f32x4*)partial;  // 4096 vectors
    float s = 0.0f;
    int i = threadIdx.x;
#pragma unroll
    for (int c = 0; c < 16; ++c) {
        f32x4 q = p4[i];
        s += q.x + q.y + q.z + q.w;
        i += 256;
    }
    for (int o = 32; o > 0; o >>= 1) s += __shfl_down(s, o);
    __shared__ float sr[4];
    if ((threadIdx.x & 63) == 0) sr[threadIdx.x >> 6] = s;
    __syncthreads();
    if (threadIdx.x == 0)
        out[0] = (sr[0] + sr[1] + sr[2] + sr[3]) * (1.0f / ((float)NB * (float)NC));
}

// ---------------------------------------------------------------------------
// Fallback (R6 structure) in case ws_size < ~3.9 MB: wave-per-row, NT loads.
// ---------------------------------------------------------------------------
__global__ __launch_bounds__(256, 4) void row_kernel(const float* __restrict__ x,
                                                     const int* __restrict__ nz,
                                                     const int* __restrict__ cls,
                                                     float* __restrict__ partial) {
    const int lane = threadIdx.x & 63;
    const int gwave = (blockIdx.x << 2) | (threadIdx.x >> 6);

#pragma unroll
    for (int r = 0; r < 2; ++r) {
        const int row = gwave * 2 + r;
        const int b = row & (NB - 1);
        const float* rp = x + (size_t)row * NC;
        const int peel = (4 - (row & 3)) & 3;
        const int rem = NC - peel;
        const int nvec = rem >> 2;
        const int tail = rem & 3;
        const f32x4* vp = (const f32x4*)(rp + peel);

        const int n = nz[b];
        float xg = (lane < n) ? rp[cls[b * 64 + lane]] : -INFINITY;
        float ex1 = (lane < peel) ? rp[lane] : -INFINITY;
        float ex2 = (lane < tail) ? rp[peel + (nvec << 2) + lane] : -INFINITY;
        float s = fexp(ex1) + fexp(ex2);

        int i = lane;
#pragma unroll
        for (int c = 0; c < 7; ++c) {
            f32x4 q0 = __builtin_nontemporal_load(vp + i);
            f32x4 q1 = __builtin_nontemporal_load(vp + i + 64);
            f32x4 q2 = __builtin_nontemporal_load(vp + i + 128);
            f32x4 q3 = __builtin_nontemporal_load(vp + i + 192);
            s += fexp(q0.x) + fexp(q0.y) + fexp(q0.z) + fexp(q0.w);
            s += fexp(q1.x) + fexp(q1.y) + fexp(q1.z) + fexp(q1.w);
            s += fexp(q2.x) + fexp(q2.y) + fexp(q2.z) + fexp(q2.w);
            s += fexp(q3.x) + fexp(q3.y) + fexp(q3.z) + fexp(q3.w);
            i += 256;
        }
        if (i < nvec) {
            f32x4 q = __builtin_nontemporal_load(vp + i);
            s += fexp(q.x) + fexp(q.y) + fexp(q.z) + fexp(q.w);
        }
        float z = fexp(xg);
        for (int o = 32; o > 0; o >>= 1) {
            s += __shfl_down(s, o);
            z += __shfl_down(z, o);
        }
        if (lane == 0) partial[row] = 1.0f - z / s;
    }
}

extern "C" void kernel_launch(void* const* d_in, const int* in_sizes, int n_in,
                              void* d_out, int out_size, void* d_ws, size_t ws_size,
                              hipStream_t stream) {
    const float* dense_pred = (const float*)d_in[0];
    const int* target = (const int*)d_in[1];
    float* out = (float*)d_out;

    // Workspace layout (phase-1 path):
    //   win:     float2[NWIN]   @ 0          (3,766,784 B)
    //   nz:      int[64]        @ 3,766,784
    //   cls:     int[64*64]     @ +256
    //   partial: float[16384]   @ 3,783,424  (16B aligned: /16 = 236,464)
    char* ws = (char*)d_ws;
    float2* win = (float2*)ws;
    int* nz = (int*)(ws + (size_t)NWIN * 8);
    int* cls = nz + 64;
    float* partial = (float*)(ws + (size_t)NWIN * 8 + 256 + 64 * 64 * 4);

    const size_t need = (size_t)NWIN * 8 + 256 + 64 * 64 * 4 + NROWS * 4;

    if (ws_size >= need) {
        prep_kernel<<<1, 64, 0, stream>>>(target, nz, cls);
        stream_kernel<<<NBLK, 256, 0, stream>>>(dense_pred, win);
        row2_kernel<<<NROWS / 4, 256, 0, stream>>>(dense_pred, win, nz, cls, partial);
        final_kernel<<<1, 256, 0, stream>>>(partial, out);
    } else {
        // Fallback: small-workspace layout (R6 structure)
        int* nz2 = (int*)d_ws;
        int* cls2 = nz2 + 64;
        float* partial2 = (float*)(cls2 + 64 * 64);
        prep_kernel<<<1, 64, 0, stream>>>(target, nz2, cls2);
        row_kernel<<<NBLK, 256, 0, stream>>>(dense_pred, nz2, cls2, partial2);
        final_kernel<<<1, 256, 0, stream>>>(partial2, out);
    }
}

// Round 9
// 204.047 us; speedup vs baseline: 2.4813x; 1.0212x over previous
//
#include <hip/hip_runtime.h>
#include <math.h>

// Problem constants: T=256, NB=64, NCLASS=7357, L=50
#define TT 256
#define NB 64
#define NC 7357
#define LL 50
#define NROWS (TT * NB)           // 16384
#define NFLOAT (NROWS * NC)       // 120,537,088 floats = 58,856 * 2048 exactly
#define SW 2048                   // superwindow: floats per wave-iteration
#define NSW (NFLOAT / SW)         // 58,856 superwindows (no tail)
#define NBLK 2048

typedef float f32x4 __attribute__((ext_vector_type(4)));

// ---------------------------------------------------------------------------
// Kernel 1: per-batch unique zeroed-class lists.
// ---------------------------------------------------------------------------
__global__ void prep_kernel(const int* __restrict__ target,
                            int* __restrict__ nz, int* __restrict__ cls) {
    int b = threadIdx.x;
    if (b >= NB) return;
    int list[LL + 1];
    int n = 0;
    list[n++] = 0;
    for (int j = 0; j < LL; ++j) {
        int t = target[b * LL + j];
        if (t == 0) break;
        bool found = false;
        for (int k = 0; k < n; ++k)
            if (list[k] == t) { found = true; break; }
        if (!found) list[n++] = t;
    }
    nz[b] = n;
    for (int k = 0; k < n; ++k) cls[b * 64 + k] = list[k];
}

__device__ __forceinline__ float fexp(float v) { return __expf(v); }

// ---------------------------------------------------------------------------
// Kernel 2 (PHASE 1): deep-MLP streaming sweep. Each wave-iteration covers a
// 2048-float superwindow via 8 INDEPENDENT nontemporal dwordx4 loads per lane,
// all issued before any consumption (8 KB outstanding per wave). This is the
// R9 lever: every prior kernel had MLP 1-4 per wave and all capped at
// ~2.5-3.2 TB/s read; writes (no latency to cover) hit 6.7 TB/s on the same
// chip -> hypothesis: reads are latency*MLP-bound, not DRAM-bound.
// A superwindow spans at most ONE row boundary (2048 < 7357): the wave writes
// float2{sum in first row, sum in next row}.
// ---------------------------------------------------------------------------
__global__ __launch_bounds__(256, 4) void stream_kernel(const float* __restrict__ x,
                                                        float2* __restrict__ win) {
    const int lane = threadIdx.x & 63;
    const int gwave = (blockIdx.x << 2) | (threadIdx.x >> 6);  // 0..8191
    const f32x4* vp = (const f32x4*)x;

    for (int u = gwave; u < NSW; u += 8192) {
        const size_t base = (size_t)u * 512 + lane;  // float4 index
        // 8 independent loads, issued back-to-back (MLP = 8)
        f32x4 q0 = __builtin_nontemporal_load(vp + base);
        f32x4 q1 = __builtin_nontemporal_load(vp + base + 64);
        f32x4 q2 = __builtin_nontemporal_load(vp + base + 128);
        f32x4 q3 = __builtin_nontemporal_load(vp + base + 192);
        f32x4 q4 = __builtin_nontemporal_load(vp + base + 256);
        f32x4 q5 = __builtin_nontemporal_load(vp + base + 320);
        f32x4 q6 = __builtin_nontemporal_load(vp + base + 384);
        f32x4 q7 = __builtin_nontemporal_load(vp + base + 448);

        const int fbase = u << 11;               // first flat float idx
        const int r1 = fbase / NC;               // row of first element
        const int r2 = (fbase + SW - 1) / NC;    // row of last element

        float sA, sB;
        if (r1 == r2) {                          // ~72% of superwindows
            sA = fexp(q0.x) + fexp(q0.y) + fexp(q0.z) + fexp(q0.w);
            sA += fexp(q1.x) + fexp(q1.y) + fexp(q1.z) + fexp(q1.w);
            sA += fexp(q2.x) + fexp(q2.y) + fexp(q2.z) + fexp(q2.w);
            sA += fexp(q3.x) + fexp(q3.y) + fexp(q3.z) + fexp(q3.w);
            sA += fexp(q4.x) + fexp(q4.y) + fexp(q4.z) + fexp(q4.w);
            sA += fexp(q5.x) + fexp(q5.y) + fexp(q5.z) + fexp(q5.w);
            sA += fexp(q6.x) + fexp(q6.y) + fexp(q6.z) + fexp(q6.w);
            sA += fexp(q7.x) + fexp(q7.y) + fexp(q7.z) + fexp(q7.w);
            for (int o = 32; o > 0; o >>= 1) sA += __shfl_down(sA, o);
            sB = 0.0f;
        } else {                                 // boundary: split at B
            const int B = r2 * NC;
            sA = 0.0f; sB = 0.0f;
            f32x4 qs[8] = {q0, q1, q2, q3, q4, q5, q6, q7};
#pragma unroll
            for (int k = 0; k < 8; ++k) {
                const int f = fbase + ((k * 64 + lane) << 2);
                float e0 = fexp(qs[k].x), e1 = fexp(qs[k].y);
                float e2 = fexp(qs[k].z), e3 = fexp(qs[k].w);
                if (f + 0 < B) sA += e0; else sB += e0;
                if (f + 1 < B) sA += e1; else sB += e1;
                if (f + 2 < B) sA += e2; else sB += e2;
                if (f + 3 < B) sA += e3; else sB += e3;
            }
            for (int o = 32; o > 0; o >>= 1) {
                sA += __shfl_down(sA, o);
                sB += __shfl_down(sB, o);
            }
        }
        if (lane == 0) win[u] = make_float2(sA, sB);
    }
}

// ---------------------------------------------------------------------------
// Kernel 3 (PHASE 2): one wave per row. Lanes 0..4 pick up this row's
// superwindow contributions (471 KB, cache-hot); lanes 0..n-1 gather the
// <=51 zeroed-class elements; joint shfl reduce; partial = 1 - Z/S.
// ---------------------------------------------------------------------------
__global__ __launch_bounds__(256) void row2_kernel(const float* __restrict__ x,
                                                   const float2* __restrict__ win,
                                                   const int* __restrict__ nz,
                                                   const int* __restrict__ cls,
                                                   float* __restrict__ partial) {
    const int lane = threadIdx.x & 63;
    const int wave = threadIdx.x >> 6;
    const int row = (blockIdx.x << 2) | wave;   // grid 4096 -> rows 0..16383
    const int b = row & (NB - 1);

    const int f0 = row * NC;
    const int u0 = f0 >> 11;                    // first superwindow of row
    const int u1 = (f0 + NC - 1) >> 11;         // last superwindow of row

    float S = 0.0f;
    const int u = u0 + lane;
    if (u <= u1) {                              // <=5 active lanes
        float2 w = win[u];
        const int fb = u << 11;
        const int r1 = fb / NC;
        const int r2 = (fb + SW - 1) / NC;
        if (r1 == row) S += w.x;
        if (r2 == row && r1 != row) S += w.y;
    }

    // zeroed-class gather
    const int n = nz[b];
    float z = 0.0f;
    if (lane < n) z = fexp(x[(size_t)f0 + cls[b * 64 + lane]]);

    for (int o = 32; o > 0; o >>= 1) {
        S += __shfl_down(S, o);
        z += __shfl_down(z, o);
    }
    if (lane == 0) partial[row] = 1.0f - z / S;
}

// ---------------------------------------------------------------------------
// Kernel 4: deterministic final reduce of 16384 partials -> scalar loss.
// ---------------------------------------------------------------------------
__global__ __launch_bounds__(256) void final_kernel(const float* __restrict__ partial,
                                                    float* __restrict__ out) {
    const f32x4* p4 = (const f32x4*)partial;  // 4096 vectors
    float s = 0.0f;
    int i = threadIdx.x;
#pragma unroll
    for (int c = 0; c < 16; ++c) {
        f32x4 q = p4[i];
        s += q.x + q.y + q.z + q.w;
        i += 256;
    }
    for (int o = 32; o > 0; o >>= 1) s += __shfl_down(s, o);
    __shared__ float sr[4];
    if ((threadIdx.x & 63) == 0) sr[threadIdx.x >> 6] = s;
    __syncthreads();
    if (threadIdx.x == 0)
        out[0] = (sr[0] + sr[1] + sr[2] + sr[3]) * (1.0f / ((float)NB * (float)NC));
}

// ---------------------------------------------------------------------------
// Fallback (R6 structure) in case ws_size is too small: wave-per-row, NT.
// ---------------------------------------------------------------------------
__global__ __launch_bounds__(256, 4) void row_kernel(const float* __restrict__ x,
                                                     const int* __restrict__ nz,
                                                     const int* __restrict__ cls,
                                                     float* __restrict__ partial) {
    const int lane = threadIdx.x & 63;
    const int gwave = (blockIdx.x << 2) | (threadIdx.x >> 6);

#pragma unroll
    for (int r = 0; r < 2; ++r) {
        const int row = gwave * 2 + r;
        const int b = row & (NB - 1);
        const float* rp = x + (size_t)row * NC;
        const int peel = (4 - (row & 3)) & 3;
        const int rem = NC - peel;
        const int nvec = rem >> 2;
        const int tail = rem & 3;
        const f32x4* vp = (const f32x4*)(rp + peel);

        const int n = nz[b];
        float xg = (lane < n) ? rp[cls[b * 64 + lane]] : -INFINITY;
        float ex1 = (lane < peel) ? rp[lane] : -INFINITY;
        float ex2 = (lane < tail) ? rp[peel + (nvec << 2) + lane] : -INFINITY;
        float s = fexp(ex1) + fexp(ex2);

        int i = lane;
#pragma unroll
        for (int c = 0; c < 7; ++c) {
            f32x4 q0 = __builtin_nontemporal_load(vp + i);
            f32x4 q1 = __builtin_nontemporal_load(vp + i + 64);
            f32x4 q2 = __builtin_nontemporal_load(vp + i + 128);
            f32x4 q3 = __builtin_nontemporal_load(vp + i + 192);
            s += fexp(q0.x) + fexp(q0.y) + fexp(q0.z) + fexp(q0.w);
            s += fexp(q1.x) + fexp(q1.y) + fexp(q1.z) + fexp(q1.w);
            s += fexp(q2.x) + fexp(q2.y) + fexp(q2.z) + fexp(q2.w);
            s += fexp(q3.x) + fexp(q3.y) + fexp(q3.z) + fexp(q3.w);
            i += 256;
        }
        if (i < nvec) {
            f32x4 q = __builtin_nontemporal_load(vp + i);
            s += fexp(q.x) + fexp(q.y) + fexp(q.z) + fexp(q.w);
        }
        float z = fexp(xg);
        for (int o = 32; o > 0; o >>= 1) {
            s += __shfl_down(s, o);
            z += __shfl_down(z, o);
        }
        if (lane == 0) partial[row] = 1.0f - z / s;
    }
}

extern "C" void kernel_launch(void* const* d_in, const int* in_sizes, int n_in,
                              void* d_out, int out_size, void* d_ws, size_t ws_size,
                              hipStream_t stream) {
    const float* dense_pred = (const float*)d_in[0];
    const int* target = (const int*)d_in[1];
    float* out = (float*)d_out;

    // Workspace layout (main path):
    //   win:     float2[NSW]   @ 0            (470,848 B)
    //   nz:      int[64]       @ 470,848
    //   cls:     int[64*64]    @ 471,104
    //   partial: float[16384]  @ 487,488      (16B aligned: /16 = 30,468)
    char* ws = (char*)d_ws;
    float2* win = (float2*)ws;
    int* nz = (int*)(ws + (size_t)NSW * 8);
    int* cls = nz + 64;
    float* partial = (float*)(ws + (size_t)NSW * 8 + 256 + 64 * 64 * 4);

    const size_t need = (size_t)NSW * 8 + 256 + 64 * 64 * 4 + NROWS * 4;

    if (ws_size >= need) {
        prep_kernel<<<1, 64, 0, stream>>>(target, nz, cls);
        stream_kernel<<<NBLK, 256, 0, stream>>>(dense_pred, win);
        row2_kernel<<<NROWS / 4, 256, 0, stream>>>(dense_pred, win, nz, cls, partial);
        final_kernel<<<1, 256, 0, stream>>>(partial, out);
    } else {
        int* nz2 = (int*)d_ws;
        int* cls2 = nz2 + 64;
        float* partial2 = (float*)(cls2 + 64 * 64);
        prep_kernel<<<1, 64, 0, stream>>>(target, nz2, cls2);
        row_kernel<<<NBLK, 256, 0, stream>>>(dense_pred, nz2, cls2, partial2);
        final_kernel<<<1, 256, 0, stream>>>(partial2, out);
    }
}

// Round 10
// 189.335 us; speedup vs baseline: 2.6741x; 1.0777x over previous
//
#include <hip/hip_runtime.h>
#include <math.h>

// Problem constants: T=256, NB=64, NCLASS=7357, L=50
#define TT 256
#define NB 64
#define NC 7357
#define LL 50
#define NROWS (TT * NB)   // 16384

typedef float f32x4 __attribute__((ext_vector_type(4)));

// ---------------------------------------------------------------------------
// Kernel 1: per-batch unique zeroed-class lists.
// ---------------------------------------------------------------------------
__global__ void prep_kernel(const int* __restrict__ target,
                            int* __restrict__ nz, int* __restrict__ cls) {
    int b = threadIdx.x;
    if (b >= NB) return;
    int list[LL + 1];
    int n = 0;
    list[n++] = 0;
    for (int j = 0; j < LL; ++j) {
        int t = target[b * LL + j];
        if (t == 0) break;
        bool found = false;
        for (int k = 0; k < n; ++k)
            if (list[k] == t) { found = true; break; }
        if (!found) list[n++] = t;
    }
    nz[b] = n;
    for (int k = 0; k < n; ++k) cls[b * 64 + k] = list[k];
}

__device__ __forceinline__ float fexp(float v) { return __expf(v); }

// ---------------------------------------------------------------------------
// Kernel 2: ONE ROW PER WAVE (16384 waves, 4096 blocks = 2x oversubscribed so
// the HW scheduler backfills -> fine-grained tail; no serial second row per
// wave). NT dwordx4 streaming; evidence from R1-R9: HBM READ rate caps at
// ~3.16 TB/s on this part regardless of pattern/MLP (R7 direct measurement;
// m13-copy and D2D-copy arithmetic agree), so this kernel targets minimal
// non-streaming overhead around that cap, not higher BW.
// ---------------------------------------------------------------------------
__global__ __launch_bounds__(256, 4) void row_kernel(const float* __restrict__ x,
                                                     const int* __restrict__ nz,
                                                     const int* __restrict__ cls,
                                                     float* __restrict__ partial) {
    const int lane = threadIdx.x & 63;
    const int row = ((blockIdx.x << 8) | threadIdx.x) >> 6;  // 0..16383
    const int b = row & (NB - 1);
    const float* rp = x + (size_t)row * NC;

    // Row byte offset = row*29428; %16 == row*4 -> peel to 16B alignment.
    const int peel = (4 - (row & 3)) & 3;
    const int rem = NC - peel;
    const int nvec = rem >> 2;        // 1838 or 1839
    const int tail = rem & 3;
    const f32x4* vp = (const f32x4*)(rp + peel);

    // zeroed-class gather (<=51 lanes), issued early, overlaps the stream
    const int n = nz[b];
    float xg = (lane < n) ? rp[cls[b * 64 + lane]] : -INFINITY;

    // peel / tail leftovers (default -inf -> exp = 0)
    float ex1 = (lane < peel) ? rp[lane] : -INFINITY;
    float ex2 = (lane < tail) ? rp[peel + (nvec << 2) + lane] : -INFINITY;

    float s = fexp(ex1) + fexp(ex2);

    // 28 full wave-iterations (28*64 = 1792 <= 1838): 7 chunks of 4 loads.
    int i = lane;
#pragma unroll
    for (int c = 0; c < 7; ++c) {
        f32x4 q0 = __builtin_nontemporal_load(vp + i);
        f32x4 q1 = __builtin_nontemporal_load(vp + i + 64);
        f32x4 q2 = __builtin_nontemporal_load(vp + i + 128);
        f32x4 q3 = __builtin_nontemporal_load(vp + i + 192);
        s += fexp(q0.x) + fexp(q0.y) + fexp(q0.z) + fexp(q0.w);
        s += fexp(q1.x) + fexp(q1.y) + fexp(q1.z) + fexp(q1.w);
        s += fexp(q2.x) + fexp(q2.y) + fexp(q2.z) + fexp(q2.w);
        s += fexp(q3.x) + fexp(q3.y) + fexp(q3.z) + fexp(q3.w);
        i += 256;
    }
    // partial 29th iteration (46 or 47 active lanes)
    if (i < nvec) {
        f32x4 q = __builtin_nontemporal_load(vp + i);
        s += fexp(q.x) + fexp(q.y) + fexp(q.z) + fexp(q.w);
    }

    float z = fexp(xg);

    // wave-only reduction (width 64)
    for (int o = 32; o > 0; o >>= 1) {
        s += __shfl_down(s, o);
        z += __shfl_down(z, o);
    }
    if (lane == 0) partial[row] = 1.0f - z / s;
}

// ---------------------------------------------------------------------------
// Kernel 3: deterministic final reduce, 1024 threads, float4 loads.
// partial @ ws byte 16640 (16B aligned).
// ---------------------------------------------------------------------------
__global__ __launch_bounds__(1024) void final_kernel(const float* __restrict__ partial,
                                                     float* __restrict__ out) {
    const f32x4* p4 = (const f32x4*)partial;  // 4096 vectors
    float s = 0.0f;
    int i = threadIdx.x;
#pragma unroll
    for (int c = 0; c < 4; ++c) {   // 4 * 1024 = 4096
        f32x4 q = p4[i];
        s += q.x + q.y + q.z + q.w;
        i += 1024;
    }
    for (int o = 32; o > 0; o >>= 1) s += __shfl_down(s, o);
    __shared__ float sr[16];
    if ((threadIdx.x & 63) == 0) sr[threadIdx.x >> 6] = s;
    __syncthreads();
    if (threadIdx.x == 0) {
        float t = 0.0f;
#pragma unroll
        for (int w = 0; w < 16; ++w) t += sr[w];
        out[0] = t * (1.0f / ((float)NB * (float)NC));
    }
}

extern "C" void kernel_launch(void* const* d_in, const int* in_sizes, int n_in,
                              void* d_out, int out_size, void* d_ws, size_t ws_size,
                              hipStream_t stream) {
    const float* dense_pred = (const float*)d_in[0];
    const int* target = (const int*)d_in[1];
    float* out = (float*)d_out;

    // Workspace layout
    int* nz = (int*)d_ws;                     //   64 ints   (bytes 0..255)
    int* cls = nz + 64;                       //   4096 ints (bytes 256..16639)
    float* partial = (float*)(cls + 64 * 64); //   16384 floats @ byte 16640 (16B aligned)

    prep_kernel<<<1, 64, 0, stream>>>(target, nz, cls);
    row_kernel<<<NROWS / 4, 256, 0, stream>>>(dense_pred, nz, cls, partial);
    final_kernel<<<1, 1024, 0, stream>>>(partial, out);
}